// Round 1
// baseline (716.005 us; speedup 1.0000x reference)
//
#include <hip/hip_runtime.h>
#include <math.h>

// Problem constants (from reference): R=1024, C=8192, DIN=16, E=5, NREG=2048
#define RDIM 1024
#define CDIM 8192
#define DIN  16
#define EDIM 5

// Tile: 16 regions x 256 cells per block, 256 threads (4 waves)
#define RT   16
#define CT   256
#define WROW 96   // padded per-region weight row: W1 [0..79], b1 [80..84], Wf [88..92]

__global__ __launch_bounds__(256)
void e2e_kernel(const float* __restrict__ emb,   // [R, C, DIN]
                const int*   __restrict__ gidx,  // [R]
                const float* __restrict__ W1,    // [NREG, DIN, E]
                const float* __restrict__ b1,    // [NREG, E]
                const float* __restrict__ Wf,    // [NREG, E]
                float* __restrict__ out)         // [C, R]
{
    __shared__ int   s_g[RT];
    __shared__ float s_w[RT * WROW];            // 6 KiB
    __shared__ float s_tile[CT * (RT + 1)];     // 17 KiB, +1 pad -> 2-way bank alias (free)

    const int tid = threadIdx.x;
    const int c0  = blockIdx.x * CT;
    const int r0  = blockIdx.y * RT;

    if (tid < RT) s_g[tid] = gidx[r0 + tid];
    __syncthreads();

    // Stage gathered weights for this block's 16 regions into LDS.
    for (int idx = tid; idx < RT * 90; idx += 256) {
        int rl = idx / 90;
        int k  = idx - rl * 90;
        int g  = s_g[rl];
        float v; int dst;
        if (k < 80)      { v = W1[g * 80 + k];       dst = k;     }   // W1[g][i][e] at i*5+e
        else if (k < 85) { v = b1[g * 5 + (k - 80)]; dst = k;     }
        else             { v = Wf[g * 5 + (k - 85)]; dst = k + 3; }   // Wf at 88..92
        s_w[rl * WROW + dst] = v;
    }
    __syncthreads();

    const int lane = tid & 63;
    const int wv   = tid >> 6;

    // Each wave handles 4 regions; each lane handles 4 cells per region.
    #pragma unroll
    for (int q = 0; q < 4; ++q) {
        const int rl = wv * 4 + q;
        const int r  = r0 + rl;

        // Hoist this region's weights into registers (wave-uniform LDS broadcast,
        // vectorized ds_read_b128; amortized over 4 cells per lane).
        const float4* wp = (const float4*)(s_w + rl * WROW);
        float ww[80], bb[EDIM], wf[EDIM];
        #pragma unroll
        for (int q4 = 0; q4 < 20; ++q4) ((float4*)ww)[q4] = wp[q4];
        {
            float4 bt = wp[20];          // floats 80..83
            bb[0] = bt.x; bb[1] = bt.y; bb[2] = bt.z; bb[3] = bt.w;
            bb[4] = s_w[rl * WROW + 84];
            float4 ft = wp[22];          // floats 88..91
            wf[0] = ft.x; wf[1] = ft.y; wf[2] = ft.z; wf[3] = ft.w;
            wf[4] = s_w[rl * WROW + 92];
        }

        #pragma unroll
        for (int m = 0; m < 4; ++m) {
            const int cl = lane + 64 * m;
            const int c  = c0 + cl;
            const float4* p = (const float4*)(emb + ((size_t)r * CDIM + c) * DIN);
            float4 x0 = p[0], x1 = p[1], x2 = p[2], x3 = p[3];
            float x[DIN] = { x0.x, x0.y, x0.z, x0.w,
                             x1.x, x1.y, x1.z, x1.w,
                             x2.x, x2.y, x2.z, x2.w,
                             x3.x, x3.y, x3.z, x3.w };
            float acc = 0.f;
            #pragma unroll
            for (int e = 0; e < EDIM; ++e) {
                float h = bb[e];
                #pragma unroll
                for (int i = 0; i < DIN; ++i)
                    h = fmaf(x[i], ww[i * EDIM + e], h);
                // exact GELU: 0.5*x*(1+erf(x/sqrt(2)))
                h = 0.5f * h * (1.0f + erff(h * 0.70710678118654752f));
                acc = fmaf(h, wf[e], acc);
            }
            s_tile[cl * (RT + 1) + rl] = acc;
        }
    }
    __syncthreads();

    // Transposed, coalesced write-out: out[(c0+cl)*R + r0 + rl]
    const int orl  = tid & 15;
    const int ocl0 = tid >> 4;   // 0..15
    #pragma unroll
    for (int it = 0; it < 16; ++it) {
        const int cl = ocl0 + 16 * it;
        out[(size_t)(c0 + cl) * RDIM + r0 + orl] = s_tile[cl * (RT + 1) + orl];
    }
}

extern "C" void kernel_launch(void* const* d_in, const int* in_sizes, int n_in,
                              void* d_out, int out_size, void* d_ws, size_t ws_size,
                              hipStream_t stream) {
    const float* emb  = (const float*)d_in[0];
    const int*   gidx = (const int*)d_in[1];
    const float* W1   = (const float*)d_in[2];
    const float* b1   = (const float*)d_in[3];
    const float* Wf   = (const float*)d_in[4];
    float* out = (float*)d_out;

    dim3 grid(CDIM / CT, RDIM / RT);   // 32 x 64 = 2048 blocks
    dim3 block(256);
    e2e_kernel<<<grid, block, 0, stream>>>(emb, gidx, W1, b1, Wf, out);
}